// Round 5
// baseline (1068.397 us; speedup 1.0000x reference)
//
#include <hip/hip_runtime.h>
#include <math.h>
#include <stdint.h>

// VQActivation residual VQ, depth=4. x:(32,256,56,56) f32, cb:(1024,256) f32.
//
// PASSED semantics preserved exactly: decisions = np f32 sgemm = sequential
// fmaf chain over k ascending, single f32 accumulator; u = that bitwise max;
// resid -= fl(cb*u) with separate roundings; out re-summed in np's exact
// f32 add order. Candidate SELECTION (bf16-MFMA approx) only needs to
// CONTAIN the exact winner; Phase B re-ranks candidates with the exact chain.
//
// Round-7: the four falsifications (VALU cut: null; occupancy up: null;
// traffic cut 6x: null; reg-pipeline: spilled) leave ONE invariant across
// all rounds: effective prefetch distance <= 1 tile, with per-tile
// __syncthreads (R4) draining vmcnt to 0 ~100cy after issue. This round
// applies the T3/T4 counted-vmcnt schedule:
//   * TM=32, 512 thr = 8 waves (4 quarters x 2 row-blocks): fa = 32 VGPR.
//   * THREE LDS tile-buffers -> 2-tile-deep global_load_lds pipeline:
//     per tile { s_waitcnt vmcnt(4); s_barrier; stage t+2; consume t }.
//     vmcnt reaches 0 exactly once per kernel (last tile).
//   * all other barriers are { lgkmcnt(0); s_barrier } -- no vmcnt drain,
//     so next-depth tiles 0/1 fly across Phase B/C.
//   * LDS = 33,280 + 98,304 + 6,144 + 1,024 + 512 = 139,264 B (1 block/CU).

#define KDIM 256
#define KSZ  1024
#define TM   32
#define HWSZ 3136
#define NBLK (HWSZ/TM)   // 98 row-blocks per image
#define RSTR 260         // resid row stride (f32): 16B-aligned, bank-skewed
#define MAXD 8

using f32x4  = __attribute__((ext_vector_type(4))) float;
using bf16x8 = __attribute__((ext_vector_type(8))) short;

static __device__ __forceinline__ unsigned short f2bf(float f) {
    unsigned u = __float_as_uint(f);
    u += 0x7fffu + ((u >> 16) & 1u);
    return (unsigned short)(u >> 16);
}

static __device__ __forceinline__ unsigned umax(unsigned a, unsigned b) { return a > b ? a : b; }
static __device__ __forceinline__ unsigned umin(unsigned a, unsigned b) { return a < b ? a : b; }

// 8 f32 -> 8 bf16 via 4x v_cvt_pk_bf16_f32 (lo = first operand, RNE).
static __device__ __forceinline__ bf16x8 pk8(const float4 a, const float4 b) {
    union { unsigned u[4]; bf16x8 v; } r;
    asm("v_cvt_pk_bf16_f32 %0, %1, %2" : "=v"(r.u[0]) : "v"(a.x), "v"(a.y));
    asm("v_cvt_pk_bf16_f32 %0, %1, %2" : "=v"(r.u[1]) : "v"(a.z), "v"(a.w));
    asm("v_cvt_pk_bf16_f32 %0, %1, %2" : "=v"(r.u[2]) : "v"(b.x), "v"(b.y));
    asm("v_cvt_pk_bf16_f32 %0, %1, %2" : "=v"(r.u[3]) : "v"(b.z), "v"(b.w));
    return r.v;
}

// insert key into sorted-desc (q1>=q2>=q3>=q4): 7 min/max ops
static __device__ __forceinline__ void insk4(unsigned k,
    unsigned& q1, unsigned& q2, unsigned& q3, unsigned& q4) {
    unsigned t1 = umin(q1, k); q1 = umax(q1, k);
    unsigned t2 = umin(q2, t1); q2 = umax(q2, t1);
    unsigned t3 = umin(q3, t2); q3 = umax(q3, t2);
    q4 = umax(q4, t3);
}

// async global->LDS DMA, 16 B per lane. LDS dest = wave-uniform base + lane*16.
#define GLOADLDS16(GP, LP)                                                     \
    __builtin_amdgcn_global_load_lds(                                          \
        (const __attribute__((address_space(1))) void*)(GP),                   \
        (__attribute__((address_space(3))) void*)(LP), 16, 0, 0)

#define BAR_LGKM()                                                             \
    { asm volatile("s_waitcnt lgkmcnt(0)" ::: "memory");                       \
      __builtin_amdgcn_s_barrier(); }

// ---- pack cb f32 [1024][256] into MFMA-B-fragment-native bf16 (512 KB) ----
// frag f = (tg*8 + kt)*64 + lane ; lane = n + 16*q holds
// cb[tg*16+n][kt*32 + q*8 + 0..7] as 8 bf16 (16 B).
__global__ __launch_bounds__(256)
void make_cb_frag(const float* __restrict__ cb, bf16x8* __restrict__ cbf)
{
    const int f    = blockIdx.x * 256 + threadIdx.x;   // 0..32767
    const int lane = f & 63, kt = (f >> 6) & 7, tg = f >> 9;
    const int n = lane & 15, q = lane >> 4;
    const float* src = cb + ((size_t)(tg * 16 + n)) * KDIM + kt * 32 + q * 8;
    const float4 a = ((const float4*)src)[0];
    const float4 b = ((const float4*)src)[1];
    bf16x8 s;
    s[0] = (short)f2bf(a.x); s[1] = (short)f2bf(a.y);
    s[2] = (short)f2bf(a.z); s[3] = (short)f2bf(a.w);
    s[4] = (short)f2bf(b.x); s[5] = (short)f2bf(b.y);
    s[6] = (short)f2bf(b.z); s[7] = (short)f2bf(b.w);
    cbf[f] = s;
}

__global__ __launch_bounds__(512, 2)
void vq_kernel(const float* __restrict__ x,
               const float* __restrict__ cb,
               const bf16x8* __restrict__ cbf,
               const int*   __restrict__ depth_p,
               float*       __restrict__ out)
{
    __shared__ __align__(16) float resid[TM][RSTR];     // 33,280 B
    __shared__ __align__(16) char  Bst[3 * 4 * 8192];   // 98,304 B [buf][q][8KB]
    __shared__ __align__(16) unsigned entK[TM][4][12];  //  6,144 B
    __shared__ float          u_all[MAXD][TM];          //  1,024 B
    __shared__ unsigned short c_all[MAXD][TM];          //    512 B
                                                        // = 139,264 B

    const int tid  = threadIdx.x;
    const int bidx = blockIdx.x;
    const int b    = bidx / NBLK;
    const int hw0  = (bidx % NBLK) * TM;
    const int depth = depth_p[0];
    const int lane = tid & 63;
    const int wv   = tid >> 6;           // 0..7
    const int q    = wv & 3;             // code quarter (256 codes)
    const int rb   = wv >> 2;            // row-block (16 rows)
    const int n    = lane & 15, qq = lane >> 4;
    const int wbase = q * 256;
    const int row0  = rb * 16;
    const int rot   = bidx & 15;         // per-block tile-order rotation

    // ---- stage x -> resid (coalesced along hw, 32-wide) ----
    {
        const int r = tid & 31, ks16 = tid >> 5;   // 16 dim-slices of 16
        const float* xp = x + ((size_t)b * KDIM + ks16 * 16) * HWSZ + hw0 + r;
        for (int m = 0; m < 16; ++m)
            resid[r][ks16 * 16 + m] = xp[(size_t)m * HWSZ];
    }

    const bf16x8* gq = cbf + (size_t)q * 8192;   // this quarter's fragments

    // wave (q,rb) stages fragments kt = rb*4 .. rb*4+3 of a tile (4 KB)
#define STAGE(PS, BS)                                                          \
    {                                                                          \
        const bf16x8* g_ = gq + (size_t)(PS) * 512 + (rb * 4) * 64 + lane;     \
        char* lb_ = Bst + (BS) * 32768 + q * 8192 + (rb * 4) * 1024;           \
        GLOADLDS16(g_ + 0 * 64, lb_ + 0 * 1024);                               \
        GLOADLDS16(g_ + 1 * 64, lb_ + 1 * 1024);                               \
        GLOADLDS16(g_ + 2 * 64, lb_ + 2 * 1024);                               \
        GLOADLDS16(g_ + 3 * 64, lb_ + 3 * 1024);                               \
    }

    // pipeline prologue: tiles 0 and 1 in flight
    STAGE(rot, 0);
    STAGE((1 + rot) & 15, 1);
    BAR_LGKM();   // publishes resid; DMA stays in flight (no vmcnt drain)

    int bufc = 0;   // buffer of the tile being consumed (global tile % 3)
    for (int d = 0; d < depth; ++d) {
        // ---- A-fragments for this wave's 16 rows ----
        bf16x8 fa[8];
#pragma unroll
        for (int kt = 0; kt < 8; ++kt) {
            const float* s0 = &resid[row0 + n][kt * 32 + qq * 8];
            fa[kt] = pk8(((const float4*)s0)[0], ((const float4*)s0)[1]);
        }

        unsigned k1[4], k2[4];
#pragma unroll
        for (int e = 0; e < 4; ++e) { k1[e] = 0u; k2[e] = 0u; }

        const bool lastd = (d + 1 == depth);
        for (int t = 0; t < 16; ++t) {
            // [W1] wait this tile's DMA (keep the 4 newer ones flying)
            if (lastd && t == 15) {
                asm volatile("s_waitcnt vmcnt(0)" ::: "memory");
            } else {
                asm volatile("s_waitcnt vmcnt(4)" ::: "memory");
            }
            __builtin_amdgcn_s_barrier();   // tile t resident for all waves

            // [S] stage tile t+2 (possibly next depth's tile) into buf+2
            if (!(lastd && t >= 14)) {
                const int ts = (t + 2) & 15;
                const int ps = (ts + rot) & 15;
                int bs = bufc - 1; if (bs < 0) bs += 3;   // (bufc+2)%3
                STAGE(ps, bs);
            }

            // [C] consume tile t from buf bufc
            const char* rb_ = Bst + bufc * 32768 + q * 8192 + lane * 16;
            f32x4 A0 = {0.f, 0.f, 0.f, 0.f};
#pragma unroll
            for (int kt = 0; kt < 8; ++kt) {
                const bf16x8 bb = *(const bf16x8*)(rb_ + kt * 1024);
                A0 = __builtin_amdgcn_mfma_f32_16x16x32_bf16(fa[kt], bb, A0, 0, 0, 0);
            }
            const int pt = (t + rot) & 15;
            const unsigned rc = (unsigned)(1023 - (wbase + pt * 16 + n));
#pragma unroll
            for (int e = 0; e < 4; ++e) {
                const unsigned kk = ((__float_as_uint(A0[e]) ^ 0x80000000u)
                                     & 0xFFFFFC00u) | rc;
                const unsigned t2 = umin(k1[e], kk);
                k1[e] = umax(k1[e], kk);
                k2[e] = umax(k2[e], t2);
            }
            bufc = (bufc == 2) ? 0 : bufc + 1;
        }

        // ---- extend to top-3, merge across lane pairs (xor 1, xor 2) ----
        unsigned k3[4];
#pragma unroll
        for (int e = 0; e < 4; ++e) k3[e] = 0u;
#pragma unroll
        for (int m = 1; m <= 2; m <<= 1) {
#pragma unroll
            for (int e = 0; e < 4; ++e) {
                const unsigned o1 = __shfl_xor(k1[e], m, 64);
                const unsigned o2 = __shfl_xor(k2[e], m, 64);
                const unsigned o3 = __shfl_xor(k3[e], m, 64);
                const unsigned a1 = k1[e], a2 = k2[e], a3 = k3[e];
                k1[e] = umax(a1, o1);
                k2[e] = umax(umin(a1, o1), umax(a2, o2));
                k3[e] = umax(umax(a3, o3), umax(umin(a2, o1), umin(a1, o2)));
            }
        }
        if ((n & 3) == 0) {
            const int g = n >> 2;
#pragma unroll
            for (int e = 0; e < 4; ++e) {
                const int row = row0 + qq * 4 + e;
                entK[row][q][g * 3 + 0] = k1[e];
                entK[row][q][g * 3 + 1] = k2[e];
                entK[row][q][g * 3 + 2] = k3[e];
            }
        }
        BAR_LGKM();   // publish entK; next-depth DMA keeps flying

        // ---- Phase B+C fused: top-4 candidates, EXACT np re-rank, resid ----
        if (tid < 128) {
            const int row = tid >> 2, j = tid & 3;
            const uint4* ep = (const uint4*)&entK[row][j][0];
            const uint4 Ea = ep[0], Eb = ep[1], Ec = ep[2];
            unsigned q1 = 0u, q2 = 0u, q3 = 0u, q4 = 0u;
            insk4(Ea.x, q1, q2, q3, q4); insk4(Ea.y, q1, q2, q3, q4);
            insk4(Ea.z, q1, q2, q3, q4); insk4(Ea.w, q1, q2, q3, q4);
            insk4(Eb.x, q1, q2, q3, q4); insk4(Eb.y, q1, q2, q3, q4);
            insk4(Eb.z, q1, q2, q3, q4); insk4(Eb.w, q1, q2, q3, q4);
            insk4(Ec.x, q1, q2, q3, q4); insk4(Ec.y, q1, q2, q3, q4);
            insk4(Ec.z, q1, q2, q3, q4); insk4(Ec.w, q1, q2, q3, q4);
#pragma unroll
            for (int m = 1; m <= 2; m <<= 1) {
                const unsigned o1 = __shfl_xor(q1, m, 64);
                const unsigned o2 = __shfl_xor(q2, m, 64);
                const unsigned o3 = __shfl_xor(q3, m, 64);
                const unsigned o4 = __shfl_xor(q4, m, 64);
                insk4(o1, q1, q2, q3, q4); insk4(o2, q1, q2, q3, q4);
                insk4(o3, q1, q2, q3, q4); insk4(o4, q1, q2, q3, q4);
            }
            const unsigned sel = (j == 0) ? q1 : (j == 1) ? q2 : (j == 2) ? q3 : q4;
            const int cand = 1023 - (int)(sel & 0x3FFu);

            // exact np f32 chain: ascending k, single accumulator
            float e = 0.f;
            const float4* cbr = (const float4*)(cb + (size_t)cand * KDIM);
            const float4* rr  = (const float4*)(&resid[row][0]);
#pragma unroll 4
            for (int kk = 0; kk < 64; ++kk) {
                const float4 cv = cbr[kk];
                const float4 rv = rr[kk];
                e = fmaf(rv.x, cv.x, e); e = fmaf(rv.y, cv.y, e);
                e = fmaf(rv.z, cv.z, e); e = fmaf(rv.w, cv.w, e);
            }
            float be = e; int bc = cand;
#pragma unroll
            for (int m = 1; m <= 2; m <<= 1) {
                const float oe = __shfl_xor(be, m, 64);
                const int   oc = __shfl_xor(bc, m, 64);
                if (oe > be || (oe == be && oc < bc)) { be = oe; bc = oc; }
            }
            if (j == 0) { u_all[d][row] = be; c_all[d][row] = (unsigned short)bc; }

            // fused Phase C: resid[row][j*64..j*64+63] = fl(resid - fl(cb*u))
            const float uu = be;
            const float* cr = cb + (size_t)bc * KDIM + j * 64;
            float* rp = &resid[row][j * 64];
#pragma unroll
            for (int jj = 0; jj < 16; ++jj) {
                const float4 cv = ((const float4*)cr)[jj];
                rp[jj * 4 + 0] = __fsub_rn(rp[jj * 4 + 0], __fmul_rn(cv.x, uu));
                rp[jj * 4 + 1] = __fsub_rn(rp[jj * 4 + 1], __fmul_rn(cv.y, uu));
                rp[jj * 4 + 2] = __fsub_rn(rp[jj * 4 + 2], __fmul_rn(cv.z, uu));
                rp[jj * 4 + 3] = __fsub_rn(rp[jj * 4 + 3], __fmul_rn(cv.w, uu));
            }
        }
        BAR_LGKM();   // publish resid/u_all; next-depth DMA keeps flying
    }
#undef STAGE

    // ---- out = ((comp1+comp2)+comp3)+comp4, np's exact elementwise order ----
    {
        const int r = tid & 31, ks16 = tid >> 5;   // 16 dim-slices of 16
        float* op = out + ((size_t)b * KDIM + ks16 * 16) * HWSZ + hw0 + r;
#pragma unroll
        for (int jj = 0; jj < 4; ++jj) {
            float ax = 0.f, ay = 0.f, az = 0.f, aw = 0.f;
            for (int d = 0; d < depth; ++d) {
                const float uu = u_all[d][r];
                const float* cr = cb + (size_t)c_all[d][r] * KDIM + ks16 * 16 + jj * 4;
                const float4 cv = *(const float4*)cr;
                ax = __fadd_rn(ax, __fmul_rn(cv.x, uu));
                ay = __fadd_rn(ay, __fmul_rn(cv.y, uu));
                az = __fadd_rn(az, __fmul_rn(cv.z, uu));
                aw = __fadd_rn(aw, __fmul_rn(cv.w, uu));
            }
            op[(size_t)(jj * 4 + 0) * HWSZ] = ax;
            op[(size_t)(jj * 4 + 1) * HWSZ] = ay;
            op[(size_t)(jj * 4 + 2) * HWSZ] = az;
            op[(size_t)(jj * 4 + 3) * HWSZ] = aw;
        }
    }
}

extern "C" void kernel_launch(void* const* d_in, const int* in_sizes, int n_in,
                              void* d_out, int out_size, void* d_ws, size_t ws_size,
                              hipStream_t stream)
{
    const float* x     = (const float*)d_in[0];
    const float* cb    = (const float*)d_in[1];
    const int*   depth = (const int*)d_in[2];
    float*       out   = (float*)d_out;
    bf16x8*      cbf   = (bf16x8*)d_ws;   // 512 KB fragment-packed bf16 codebook

    hipLaunchKernelGGL(make_cb_frag, dim3(128), dim3(256), 0, stream, cb, cbf);

    const int N      = in_sizes[0] / KDIM;  // 100352 pixel rows
    const int nblock = N / TM;              // 3136
    hipLaunchKernelGGL(vq_kernel, dim3(nblock), dim3(512), 0, stream,
                       x, cb, cbf, depth, out);
}